// Round 5
// baseline (158.878 us; speedup 1.0000x reference)
//
#include <hip/hip_runtime.h>
#include <hip/hip_bf16.h>

#define T_DIM 4096
#define B_DIM 32
#define H_DIM 128
#define M_DIM (T_DIM * B_DIM)        // 131072 GEMM rows (t*B + b)
#define G_DIM 512                    // 4*H gate columns
#define TBH   ((long)M_DIM * H_DIM)  // 16777216 output elements for `outputs`

#define RPB    512                   // rows per block (row dimension)
#define NCHUNK (RPB / 32)            // 16 chunks of 32 rows
#define LSTR   136                   // LDS row stride in shorts (128 + 8 pad = 272 B, bank-balanced)
#define LBUF   (32 * LSTR)           // one staging buffer (shorts)

typedef __attribute__((ext_vector_type(8))) short short8;    // 8 bf16 = 4 VGPRs (MFMA A/B frag)
typedef __attribute__((ext_vector_type(4))) short short4v;   // 4 bf16 = 8 bytes
typedef __attribute__((ext_vector_type(4))) float floatx4;   // MFMA C/D frag

__device__ __forceinline__ unsigned short f2bf_rne(float x) {
    union { float f; unsigned int u; } v; v.f = x;
    unsigned int r = v.u + 0x7FFFu + ((v.u >> 16) & 1u);   // round-nearest-even
    return (unsigned short)(r >> 16);
}
__device__ __forceinline__ unsigned short f2bf_rh(float x) {
    union { float f; unsigned int u; } v; v.f = x;
    return (unsigned short)((v.u + 0x8000u) >> 16);        // round-half-up (cheap, ~unbiased)
}
__device__ __forceinline__ float sigm(float x) {
    return __builtin_amdgcn_rcpf(1.0f + __expf(-x));       // saturates cleanly at 0/1
}
__device__ __forceinline__ float tanh_fast(float x) {
    float e = __expf(-2.0f * __builtin_fabsf(x));          // in (0,1]
    float t = (1.0f - e) * __builtin_amdgcn_rcpf(1.0f + e);
    return __builtin_copysignf(t, x);
}
__device__ __forceinline__ short8 pack8(float4 f0, float4 f1) {
    short8 s;
    s[0] = (short)f2bf_rh(f0.x); s[1] = (short)f2bf_rh(f0.y);
    s[2] = (short)f2bf_rh(f0.z); s[3] = (short)f2bf_rh(f0.w);
    s[4] = (short)f2bf_rh(f1.x); s[5] = (short)f2bf_rh(f1.y);
    s[6] = (short)f2bf_rh(f1.z); s[7] = (short)f2bf_rh(f1.w);
    return s;
}

// blocks 0..31:  hh[b][g] = h0[b,:]·W_hh[g,:] + b_ih[g] + b_hh[g]   (fp32, 32x512)
// blocks 32..95: W_ih fp32 -> bf16 (RNE) into ws
__global__ void prep(const float* __restrict__ h0,
                     const float* __restrict__ W_hh,
                     const float* __restrict__ b_ih,
                     const float* __restrict__ b_hh,
                     const float* __restrict__ W_ih,
                     unsigned short* __restrict__ Wb,
                     float* __restrict__ hh) {
    const int tid = threadIdx.x;
    if (blockIdx.x < 32) {
        __shared__ float h0s[128];
        const int b = blockIdx.x;
        if (tid < 128) h0s[tid] = h0[b * 128 + tid];
        __syncthreads();
        for (int g = tid; g < G_DIM; g += 256) {
            float acc = b_ih[g] + b_hh[g];
            const float* wr = W_hh + g * 128;
            #pragma unroll 8
            for (int k = 0; k < 128; ++k) acc += wr[k] * h0s[k];
            hh[b * G_DIM + g] = acc;
        }
    } else {
        const int e = ((blockIdx.x - 32) * 256 + tid) * 4;   // 64*256*4 = 65536 elements
        float4 f = *(const float4*)(W_ih + e);
        short4v s;
        s[0] = (short)f2bf_rne(f.x); s[1] = (short)f2bf_rne(f.y);
        s[2] = (short)f2bf_rne(f.z); s[3] = (short)f2bf_rne(f.w);
        *(short4v*)(Wb + e) = s;
    }
}

// Fused GEMM + LSTM-cell epilogue, de-correlated dual-block layout.
// R4 lesson: one 8-wave block/CU leaves the SIMDs idle ~55% because all waves run the
// identical stream between block-wide barriers -> stalls (ds_read burst, trans burst,
// barrier) hit every wave simultaneously. Register demand (~200/thread incl. AGPRs) pins
// us at 8 waves/CU, so instead split into TWO INDEPENDENT 4-wave blocks per CU:
// block = 512 rows x 64 h-cols (colhalf), 256 threads. Each SIMD then hosts one wave from
// each block; the blocks share no barrier, so their stall phases interleave.
// Cost: X staged once per col-half (2x pack8 + 2x L2 X reads) - cheap vs the stall win.
__global__ __launch_bounds__(256, 2) void lstm_main(
    const float* __restrict__ X,              // [M,128] fp32 input rows
    const unsigned short* __restrict__ W,     // [512,128] bf16 W_ih (pre-converted, B^T layout)
    const float* __restrict__ hh,             // [32,512] fp32 precomputed
    const float* __restrict__ c0,             // [32,128] fp32
    const float* __restrict__ noise,          // [32,128] fp32
    float* __restrict__ out)                  // fp32: outputs[M*128], h_last[4096], c_last[4096]
{
    __shared__ unsigned short Xs[2 * LBUF];   // 2 x 32 rows x (128+8) bf16 = 17408 B

    const int tid  = threadIdx.x;
    const int w    = tid >> 6;       // wave 0..3
    const int lane = tid & 63;
    const int q    = lane >> 4;      // quad 0..3
    const int lr   = lane & 15;
    const int colhalf = blockIdx.x & 1;
    const int hcol = colhalf * 64 + (w << 4) + lr;   // this lane's h-column, 0..127
    const long row0 = (long)(blockIdx.x >> 1) * RPB;

    // ---- one-time: W fragments into registers (wave-private columns, all 4 gates, K=128)
    short8 wf[4][4];                 // [gate][kt] : 16 frags = 64 VGPRs
    #pragma unroll
    for (int g = 0; g < 4; ++g)
        #pragma unroll
        for (int kt = 0; kt < 4; ++kt)
            wf[g][kt] = *(const short8*)(W + (g * 128 + hcol) * 128 + kt * 32 + q * 8);

    // ---- one-time: hh seed frags + c0/noise (b = row & 31 is chunk-invariant)
    floatx4 hhf[2][4];
    float c0v[2][4], nzv[2][4];
    #pragma unroll
    for (int mt = 0; mt < 2; ++mt) {
        #pragma unroll
        for (int r = 0; r < 4; ++r) {
            const int b = mt * 16 + q * 4 + r;
            c0v[mt][r] = c0[b * 128 + hcol];
            nzv[mt][r] = noise[b * 128 + hcol];
        }
        #pragma unroll
        for (int g = 0; g < 4; ++g) {
            floatx4 a;
            #pragma unroll
            for (int r = 0; r < 4; ++r)
                a[r] = hh[(mt * 16 + q * 4 + r) * G_DIM + g * 128 + hcol];
            hhf[mt][g] = a;
        }
    }

    // ---- staging addresses: 256 threads x 16 consecutive X elements per chunk
    const int srow = tid >> 3;            // 0..31 (row within chunk)
    const int scol = (tid & 7) << 4;      // 0,16,...,112
    const float* xsrc = X + (row0 + srow) * 128 + scol;
    unsigned short* lws = &Xs[srow * LSTR + scol];

    // ---- prologue: stage chunk 0 into buf0, issue chunk 1 loads
    {
        float4 f0 = *(const float4*)(xsrc);
        float4 f1 = *(const float4*)(xsrc + 4);
        float4 f2 = *(const float4*)(xsrc + 8);
        float4 f3 = *(const float4*)(xsrc + 12);
        *(short8*)lws       = pack8(f0, f1);
        *(short8*)(lws + 8) = pack8(f2, f3);
    }
    float4 p0 = *(const float4*)(xsrc + 4096);       // chunk 1 (32*128 floats ahead)
    float4 p1 = *(const float4*)(xsrc + 4096 + 4);
    float4 p2 = *(const float4*)(xsrc + 4096 + 8);
    float4 p3 = *(const float4*)(xsrc + 4096 + 12);
    __syncthreads();

    for (int c = 0; c < NCHUNK; ++c) {
        // issue chunk c+2 loads (2 ahead; consumed next iteration)
        float4 n0 = {}, n1 = {}, n2 = {}, n3 = {};
        if (c + 2 < NCHUNK) {
            const float* s2 = xsrc + (long)(c + 2) * 4096;
            n0 = *(const float4*)(s2);
            n1 = *(const float4*)(s2 + 4);
            n2 = *(const float4*)(s2 + 8);
            n3 = *(const float4*)(s2 + 12);
        }

        // A frags from LDS (pad-stride -> bank-balanced ds_read_b128)
        const unsigned short* rb = &Xs[(c & 1) * LBUF];
        short8 af[2][4];
        #pragma unroll
        for (int mt = 0; mt < 2; ++mt)
            #pragma unroll
            for (int kt = 0; kt < 4; ++kt)
                af[mt][kt] = *(const short8*)(rb + (mt * 16 + lr) * LSTR + kt * 32 + q * 8);

        // acc seeded from register-resident hh
        floatx4 acc[2][4];
        #pragma unroll
        for (int mt = 0; mt < 2; ++mt)
            #pragma unroll
            for (int g = 0; g < 4; ++g)
                acc[mt][g] = hhf[mt][g];

        // GEMM: 32 MFMAs, all operands in registers
        #pragma unroll
        for (int kt = 0; kt < 4; ++kt)
            #pragma unroll
            for (int g = 0; g < 4; ++g) {
                acc[0][g] = __builtin_amdgcn_mfma_f32_16x16x32_bf16(af[0][kt], wf[g][kt], acc[0][g], 0, 0, 0);
                acc[1][g] = __builtin_amdgcn_mfma_f32_16x16x32_bf16(af[1][kt], wf[g][kt], acc[1][g], 0, 0, 0);
            }

        // epilogue: C/D layout col = lane&15, row = (lane>>4)*4 + reg
        const long rbase = row0 + (long)c * 32;
        const bool last = (rbase == M_DIM - 32);      // whole last chunk is t = T-1
        #pragma unroll
        for (int mt = 0; mt < 2; ++mt)
            #pragma unroll
            for (int r = 0; r < 4; ++r) {
                const long row = rbase + mt * 16 + q * 4 + r;
                const float gi = sigm(acc[mt][0][r]);
                const float gf = sigm(acc[mt][1][r]);
                const float gg = tanh_fast(acc[mt][2][r]);
                const float go = sigm(acc[mt][3][r]);
                const float cc = gf * c0v[mt][r] + gi * gg;
                const float hv = go * tanh_fast(cc) + nzv[mt][r];
                out[row * 128 + hcol] = hv;
                if (last) {
                    const int b = mt * 16 + q * 4 + r;
                    out[TBH +        b * 128 + hcol] = hv;
                    out[TBH + 4096 + b * 128 + hcol] = cc;
                }
            }

        // write chunk c+1 into the other buffer (loads were issued last iteration ->
        // HBM latency hidden under this chunk's MFMA + epilogue)
        if (c + 1 < NCHUNK) {
            unsigned short* d = lws + ((c + 1) & 1) * LBUF;
            *(short8*)d       = pack8(p0, p1);
            *(short8*)(d + 8) = pack8(p2, p3);
        }
        __syncthreads();
        p0 = n0; p1 = n1; p2 = n2; p3 = n3;
    }
}

extern "C" void kernel_launch(void* const* d_in, const int* in_sizes, int n_in,
                              void* d_out, int out_size, void* d_ws, size_t ws_size,
                              hipStream_t stream) {
    const float* X     = (const float*)d_in[0];
    const float* h0    = (const float*)d_in[1];
    const float* c0    = (const float*)d_in[2];
    const float* noise = (const float*)d_in[3];
    const float* W_ih  = (const float*)d_in[4];
    const float* W_hh  = (const float*)d_in[5];
    const float* b_ih  = (const float*)d_in[6];
    const float* b_hh  = (const float*)d_in[7];

    unsigned short* Wb = (unsigned short*)d_ws;              // [512*128] bf16 = 128 KB
    float* hh = (float*)((char*)d_ws + 512 * 128 * sizeof(unsigned short));  // 64 KB
    float* out = (float*)d_out;

    prep<<<dim3(96), dim3(256), 0, stream>>>(h0, W_hh, b_ih, b_hh, W_ih, Wb, hh);
    // grid = row-groups x 2 col-halves; 512 blocks of 4 waves = 2 independent blocks/CU
    lstm_main<<<dim3((M_DIM / RPB) * 2), dim3(256), 0, stream>>>(X, Wb, hh, c0, noise, out);
}

// Round 6
// 149.655 us; speedup vs baseline: 1.0616x; 1.0616x over previous
//
#include <hip/hip_runtime.h>
#include <hip/hip_bf16.h>

#define T_DIM 4096
#define B_DIM 32
#define H_DIM 128
#define M_DIM (T_DIM * B_DIM)        // 131072 GEMM rows (t*B + b)
#define G_DIM 512                    // 4*H gate columns
#define TBH   ((long)M_DIM * H_DIM)  // 16777216 output elements for `outputs`

#define RPB    512                   // rows per persistent block: 256 blocks = 1 block/CU
#define NCHUNK (RPB / 32)            // 16 chunks of 32 rows
#define LSTR   136                   // LDS row stride in shorts (128 + 8 pad = 272 B, bank-balanced)
#define LBUF   (32 * LSTR)           // one staging buffer (shorts)

typedef __attribute__((ext_vector_type(8))) short short8;    // 8 bf16 = 4 VGPRs (MFMA A/B frag)
typedef __attribute__((ext_vector_type(4))) short short4v;   // 4 bf16 = 8 bytes
typedef __attribute__((ext_vector_type(4))) float floatx4;   // MFMA C/D frag

__device__ __forceinline__ unsigned short f2bf_rne(float x) {
    union { float f; unsigned int u; } v; v.f = x;
    unsigned int r = v.u + 0x7FFFu + ((v.u >> 16) & 1u);   // round-nearest-even
    return (unsigned short)(r >> 16);
}
__device__ __forceinline__ unsigned short f2bf_rh(float x) {
    union { float f; unsigned int u; } v; v.f = x;
    return (unsigned short)((v.u + 0x8000u) >> 16);        // round-half-up (cheap, ~unbiased)
}
__device__ __forceinline__ float ex2(float x) { return __builtin_amdgcn_exp2f(x); }   // v_exp_f32
__device__ __forceinline__ float rcpf(float x) { return __builtin_amdgcn_rcpf(x); }   // v_rcp_f32
__device__ __forceinline__ short8 pack8(float4 f0, float4 f1) {
    short8 s;
    s[0] = (short)f2bf_rh(f0.x); s[1] = (short)f2bf_rh(f0.y);
    s[2] = (short)f2bf_rh(f0.z); s[3] = (short)f2bf_rh(f0.w);
    s[4] = (short)f2bf_rh(f1.x); s[5] = (short)f2bf_rh(f1.y);
    s[6] = (short)f2bf_rh(f1.z); s[7] = (short)f2bf_rh(f1.w);
    return s;
}

// blocks 0..31:  hh[b][g] = h0[b,:]·W_hh[g,:] + b_ih[g] + b_hh[g]   (fp32, 32x512)
// blocks 32..95: W_ih fp32 -> bf16 (RNE) into ws
__global__ void prep(const float* __restrict__ h0,
                     const float* __restrict__ W_hh,
                     const float* __restrict__ b_ih,
                     const float* __restrict__ b_hh,
                     const float* __restrict__ W_ih,
                     unsigned short* __restrict__ Wb,
                     float* __restrict__ hh) {
    const int tid = threadIdx.x;
    if (blockIdx.x < 32) {
        __shared__ float h0s[128];
        const int b = blockIdx.x;
        if (tid < 128) h0s[tid] = h0[b * 128 + tid];
        __syncthreads();
        for (int g = tid; g < G_DIM; g += 256) {
            float acc = b_ih[g] + b_hh[g];
            const float* wr = W_hh + g * 128;
            #pragma unroll 8
            for (int k = 0; k < 128; ++k) acc += wr[k] * h0s[k];
            hh[b * G_DIM + g] = acc;
        }
    } else {
        const int e = ((blockIdx.x - 32) * 256 + tid) * 4;   // 64*256*4 = 65536 elements
        float4 f = *(const float4*)(W_ih + e);
        short4v s;
        s[0] = (short)f2bf_rne(f.x); s[1] = (short)f2bf_rne(f.y);
        s[2] = (short)f2bf_rne(f.z); s[3] = (short)f2bf_rne(f.w);
        *(short4v*)(Wb + e) = s;
    }
}

// Persistent-block fused GEMM + LSTM-cell epilogue (R1 schedule — the best measured).
// R4/R5 post-mortem: the kernel is ISSUE-BOUND on the epilogue (quarter-rate trans ops
// occupy the SIMD issue port ~8 cyc each at wave64; 10 trans + 23 VALU per element
// ~= 27us/SIMD of pure issue). So this round cuts issued work, not scheduling:
//  (a) merged-rcp algebra: i*tanh(g) = (Eg-1)*rcp((1+Ei)(Eg+1)); o*tanh(c) likewise;
//      tanh overflow-guard dropped (exp2 args bounded ~15 here). 10->8 trans, 23->18 VALU.
//  (b) acc seeded via MFMA C-in from hhf (kills 32 v_mov per wave per chunk).
__global__ __launch_bounds__(512, 2) void lstm_main(
    const float* __restrict__ X,              // [M,128] fp32 input rows
    const unsigned short* __restrict__ W,     // [512,128] bf16 W_ih (pre-converted, B^T layout)
    const float* __restrict__ hh,             // [32,512] fp32 precomputed
    const float* __restrict__ c0,             // [32,128] fp32
    const float* __restrict__ noise,          // [32,128] fp32
    float* __restrict__ out)                  // fp32: outputs[M*128], h_last[4096], c_last[4096]
{
    __shared__ unsigned short Xs[2 * LBUF];   // 2 x 32 rows x (128+8) bf16 = 17408 B

    const int tid  = threadIdx.x;
    const int w    = tid >> 6;       // wave 0..7
    const int lane = tid & 63;
    const int q    = lane >> 4;      // quad 0..3
    const int lr   = lane & 15;
    const int hcol = (w << 4) + lr;  // this lane's h-column, 0..127
    const long row0 = (long)blockIdx.x * RPB;

    // ---- one-time: W fragments into registers (wave-private columns, all 4 gates, K=128)
    short8 wf[4][4];                 // [gate][kt] : 16 frags = 64 VGPRs
    #pragma unroll
    for (int g = 0; g < 4; ++g)
        #pragma unroll
        for (int kt = 0; kt < 4; ++kt)
            wf[g][kt] = *(const short8*)(W + (g * 128 + hcol) * 128 + kt * 32 + q * 8);

    // ---- one-time: hh seed frags + c0/noise (b = row & 31 is chunk-invariant)
    floatx4 hhf[2][4];
    float c0v[2][4], nzv[2][4];
    #pragma unroll
    for (int mt = 0; mt < 2; ++mt) {
        #pragma unroll
        for (int r = 0; r < 4; ++r) {
            const int b = mt * 16 + q * 4 + r;
            c0v[mt][r] = c0[b * 128 + hcol];
            nzv[mt][r] = noise[b * 128 + hcol];
        }
        #pragma unroll
        for (int g = 0; g < 4; ++g) {
            floatx4 a;
            #pragma unroll
            for (int r = 0; r < 4; ++r)
                a[r] = hh[(mt * 16 + q * 4 + r) * G_DIM + g * 128 + hcol];
            hhf[mt][g] = a;
        }
    }

    // ---- staging addresses: thread handles 8 consecutive X elements per chunk
    const int srow = tid >> 4;            // 0..31 (row within chunk)
    const int scol = (tid & 15) << 3;     // 0,8,...,120
    const float* xsrc = X + (row0 + srow) * 128 + scol;
    unsigned short* lws = &Xs[srow * LSTR + scol];

    // ---- prologue: stage chunk 0 into buf0, issue chunk 1 loads
    {
        float4 f0 = *(const float4*)(xsrc);
        float4 f1 = *(const float4*)(xsrc + 4);
        *(short8*)lws = pack8(f0, f1);
    }
    float4 p0 = *(const float4*)(xsrc + 4096);       // chunk 1 (32*128 floats ahead)
    float4 p1 = *(const float4*)(xsrc + 4096 + 4);
    __syncthreads();

    const float K1  = 1.44269504f;       // log2(e)
    const float K2  = 2.88539008f;       // 2*log2(e)

    for (int c = 0; c < NCHUNK; ++c) {
        // issue chunk c+2 loads (2 ahead; consumed next iteration)
        float4 n0 = {}, n1 = {};
        if (c + 2 < NCHUNK) {
            n0 = *(const float4*)(xsrc + (long)(c + 2) * 4096);
            n1 = *(const float4*)(xsrc + (long)(c + 2) * 4096 + 4);
        }

        // A frags from LDS (pad-stride -> bank-balanced ds_read_b128)
        const unsigned short* rb = &Xs[(c & 1) * LBUF];
        short8 af[2][4];
        #pragma unroll
        for (int mt = 0; mt < 2; ++mt)
            #pragma unroll
            for (int kt = 0; kt < 4; ++kt)
                af[mt][kt] = *(const short8*)(rb + (mt * 16 + lr) * LSTR + kt * 32 + q * 8);

        // GEMM: 32 MFMAs; kt=0 seeds from register-resident hhf (C-in), rest accumulate
        floatx4 acc[2][4];
        #pragma unroll
        for (int g = 0; g < 4; ++g) {
            acc[0][g] = __builtin_amdgcn_mfma_f32_16x16x32_bf16(af[0][0], wf[g][0], hhf[0][g], 0, 0, 0);
            acc[1][g] = __builtin_amdgcn_mfma_f32_16x16x32_bf16(af[1][0], wf[g][0], hhf[1][g], 0, 0, 0);
        }
        #pragma unroll
        for (int kt = 1; kt < 4; ++kt)
            #pragma unroll
            for (int g = 0; g < 4; ++g) {
                acc[0][g] = __builtin_amdgcn_mfma_f32_16x16x32_bf16(af[0][kt], wf[g][kt], acc[0][g], 0, 0, 0);
                acc[1][g] = __builtin_amdgcn_mfma_f32_16x16x32_bf16(af[1][kt], wf[g][kt], acc[1][g], 0, 0, 0);
            }

        // epilogue: C/D layout col = lane&15, row = (lane>>4)*4 + reg
        // merged-rcp algebra: sigm(a)*tanh(b) = (Eb-1) * rcp((1+Ea)(Eb+1))
        //   with Ea = 2^(-K1*a), Eb = 2^(K2*b).  8 trans + ~18 VALU per element.
        const long rbase = row0 + (long)c * 32;
        const bool last = (rbase == M_DIM - 32);      // whole last chunk is t = T-1
        #pragma unroll
        for (int mt = 0; mt < 2; ++mt)
            #pragma unroll
            for (int r = 0; r < 4; ++r) {
                const long row = rbase + mt * 16 + q * 4 + r;
                const float ai = acc[mt][0][r];
                const float af_ = acc[mt][1][r];
                const float ag = acc[mt][2][r];
                const float ao = acc[mt][3][r];
                const float Ei = ex2(-K1 * ai);
                const float Ef = ex2(-K1 * af_);
                const float Eg = ex2( K2 * ag);
                const float Eo = ex2(-K1 * ao);
                const float ig = (Eg - 1.0f) * rcpf((1.0f + Ei) * (Eg + 1.0f));  // sigm(ai)*tanh(ag)
                const float gf = rcpf(1.0f + Ef);                                // sigm(af)
                const float cc = __builtin_fmaf(gf, c0v[mt][r], ig);
                const float Ec = ex2( K2 * cc);
                const float ot = (Ec - 1.0f) * rcpf((1.0f + Eo) * (Ec + 1.0f));  // sigm(ao)*tanh(cc)
                const float hv = ot + nzv[mt][r];
                out[row * 128 + hcol] = hv;
                if (last) {
                    const int b = mt * 16 + q * 4 + r;
                    out[TBH +        b * 128 + hcol] = hv;
                    out[TBH + 4096 + b * 128 + hcol] = cc;
                }
            }

        // write chunk c+1 into the other buffer (loads were issued last iteration ->
        // HBM latency hidden under this chunk's MFMA + epilogue)
        if (c + 1 < NCHUNK)
            *(short8*)(lws + ((c + 1) & 1) * LBUF) = pack8(p0, p1);
        __syncthreads();
        p0 = n0; p1 = n1;
    }
}

extern "C" void kernel_launch(void* const* d_in, const int* in_sizes, int n_in,
                              void* d_out, int out_size, void* d_ws, size_t ws_size,
                              hipStream_t stream) {
    const float* X     = (const float*)d_in[0];
    const float* h0    = (const float*)d_in[1];
    const float* c0    = (const float*)d_in[2];
    const float* noise = (const float*)d_in[3];
    const float* W_ih  = (const float*)d_in[4];
    const float* W_hh  = (const float*)d_in[5];
    const float* b_ih  = (const float*)d_in[6];
    const float* b_hh  = (const float*)d_in[7];

    unsigned short* Wb = (unsigned short*)d_ws;              // [512*128] bf16 = 128 KB
    float* hh = (float*)((char*)d_ws + 512 * 128 * sizeof(unsigned short));  // 64 KB
    float* out = (float*)d_out;

    prep<<<dim3(96), dim3(256), 0, stream>>>(h0, W_hh, b_ih, b_hh, W_ih, Wb, hh);
    lstm_main<<<dim3(M_DIM / RPB), dim3(512), 0, stream>>>(X, Wb, hh, c0, noise, out);
}